// Round 12
// baseline (286.598 us; speedup 1.0000x reference)
//
#include <hip/hip_runtime.h>
#include <hip/hip_bf16.h>
#include <hip/hip_fp16.h>
#include <math.h>

#define N_NODES 50000
#define N_EDGES 1600000
#define D_IN    32
#define HID     64
#define HEADS   4
#define D_OUT   32
#define NEG_SLOPE 0.2f
#define CHUNK 128
#define NTILES 3125   // N_NODES / 16, exact

// MSD bucket-sort CSR build
#define NBKT 196      // d>>8 buckets (d < 50000)
#define NBLK_A 391    // ceil(1.6M / 4096)
#define TILE_A 4096
#define GH (NBKT * NBLK_A)   // 76636
#define NSB 300       // ceil(GH / 256)
#define CAP 10240     // max bucket size (avg 8163, sigma ~90 -> 23 sigma margin)

typedef _Float16 half8 __attribute__((ext_vector_type(8)));
typedef float    f32x4 __attribute__((ext_vector_type(4)));
typedef float    f32x2 __attribute__((ext_vector_type(2)));

// ---------------------------------------------------------------- CSR: pass A — per-block 196-bin histogram (LDS, per-wave replicas)
__global__ __launch_bounds__(256) void histA(const int* __restrict__ edge,
                                             int* __restrict__ ghist) {
    __shared__ int hist[4][NBKT];
    int t = threadIdx.x, wv = t >> 6;
    for (int i = t; i < 4 * NBKT; i += 256) ((int*)hist)[i] = 0;
    __syncthreads();
    int base = blockIdx.x * TILE_A;
#pragma unroll
    for (int k = 0; k < 16; k++) {
        int i = base + k * 256 + t;
        if (i < N_EDGES) atomicAdd(&hist[wv][edge[N_EDGES + i] >> 8], 1);
    }
    __syncthreads();
    for (int b = t; b < NBKT; b += 256)
        ghist[b * NBLK_A + blockIdx.x] = hist[0][b] + hist[1][b] + hist[2][b] + hist[3][b];
}

// ---------------------------------------------------------------- CSR: pass B — hierarchical coalesced scan of GH entries
__global__ __launch_bounds__(256) void scanB1(const int* __restrict__ g,
                                              int* __restrict__ bsum) {
    int t = threadIdx.x;
    int i = blockIdx.x * 256 + t;
    int v = (i < GH) ? g[i] : 0;              // coalesced
#pragma unroll
    for (int off = 32; off; off >>= 1) v += __shfl_xor(v, off);
    __shared__ int ws[4];
    if ((t & 63) == 0) ws[t >> 6] = v;
    __syncthreads();
    if (t == 0) bsum[blockIdx.x] = ws[0] + ws[1] + ws[2] + ws[3];
}

__global__ __launch_bounds__(320) void scanB2(int* __restrict__ bsum) {
    int t = threadIdx.x, lane = t & 63, wv = t >> 6;
    int v = (t < NSB) ? bsum[t] : 0;
    int inc = v;
#pragma unroll
    for (int d = 1; d < 64; d <<= 1) {
        int u = __shfl_up(inc, d);
        if (lane >= d) inc += u;
    }
    __shared__ int ws[5];
    if (lane == 63) ws[wv] = inc;
    __syncthreads();
    int add = 0;
#pragma unroll
    for (int j = 0; j < 5; j++) if (j < wv) add += ws[j];
    if (t < NSB) bsum[t] = add + inc - v;     // exclusive block offsets
}

__global__ __launch_bounds__(256) void scanB3(int* __restrict__ g,
                                              const int* __restrict__ bsum) {
    int t = threadIdx.x, lane = t & 63, wv = t >> 6;
    int i = blockIdx.x * 256 + t;
    int v = (i < GH) ? g[i] : 0;              // coalesced
    int inc = v;
#pragma unroll
    for (int d = 1; d < 64; d <<= 1) {
        int u = __shfl_up(inc, d);
        if (lane >= d) inc += u;
    }
    __shared__ int ws[4];
    if (lane == 63) ws[wv] = inc;
    __syncthreads();
    int add = 0;
#pragma unroll
    for (int j = 0; j < 4; j++) if (j < wv) add += ws[j];
    if (i < GH) g[i] = bsum[blockIdx.x] + add + inc - v;   // exclusive prefix
}

// ---------------------------------------------------------------- CSR: pass C — scatter packed (d<<16|s) via LDS cursors (disjoint global ranges)
__global__ __launch_bounds__(256) void scatterC(const int* __restrict__ edge,
                                                const int* __restrict__ ghist,
                                                unsigned* __restrict__ tmp) {
    __shared__ int cur[NBKT];
    int t = threadIdx.x;
    if (t < NBKT) cur[t] = ghist[t * NBLK_A + blockIdx.x];
    __syncthreads();
    int base = blockIdx.x * TILE_A;
#pragma unroll
    for (int k = 0; k < 16; k++) {
        int i = base + k * 256 + t;
        if (i < N_EDGES) {
            int s = edge[i], d = edge[N_EDGES + i];
            int pos = atomicAdd(&cur[d >> 8], 1);     // LDS atomic
            tmp[pos] = ((unsigned)d << 16) | (unsigned)s;
        }
    }
}

// ---------------------------------------------------------------- CSR: pass D — per-bucket 256-bin regroup; emits colidx(u16), rowptr, dinv
__global__ __launch_bounds__(256) void sortD(const unsigned* __restrict__ tmp,
                                             const int* __restrict__ ghist,
                                             unsigned short* __restrict__ colidx,
                                             int* __restrict__ rowptr,
                                             float* __restrict__ dinv) {
    __shared__ unsigned char  dl8[CAP];
    __shared__ unsigned short s16[CAP];
    __shared__ unsigned short o16[CAP];
    __shared__ int hist[4][256];
    __shared__ int excl[256];
    __shared__ int wsum[4];
    int t = threadIdx.x, lane = t & 63, wv = t >> 6;
    int b = blockIdx.x;
    int lo = ghist[b * NBLK_A];
    int hi = (b < NBKT - 1) ? ghist[(b + 1) * NBLK_A] : N_EDGES;
    int size = hi - lo;
    if (size > CAP) size = CAP;           // unreachable safety clamp
    for (int i = t; i < 4 * 256; i += 256) ((int*)hist)[i] = 0;
    __syncthreads();
    for (int i = t; i < size; i += 256) {
        unsigned key = tmp[lo + i];
        int dl = (key >> 16) & 255;
        dl8[i] = (unsigned char)dl;
        s16[i] = (unsigned short)(key & 0xFFFF);
        atomicAdd(&hist[wv][dl], 1);
    }
    __syncthreads();
    int h = hist[0][t] + hist[1][t] + hist[2][t] + hist[3][t];
    int inc = h;
#pragma unroll
    for (int d = 1; d < 64; d <<= 1) {
        int u = __shfl_up(inc, d);
        if (lane >= d) inc += u;
    }
    if (lane == 63) wsum[wv] = inc;
    __syncthreads();
    int add = 0;
#pragma unroll
    for (int j = 0; j < 4; j++) if (j < wv) add += wsum[j];
    int ex = inc - h + add;
    excl[t] = ex;
    int node = b * 256 + t;
    if (node < N_NODES) {
        rowptr[node] = lo + ex;
        dinv[node]   = rsqrtf((float)(h + 1));        // +1 self-loop
    }
    if (b == NBKT - 1 && t == 0) rowptr[N_NODES] = N_EDGES;
    __syncthreads();
    for (int i = t; i < size; i += 256) {
        int pos = atomicAdd(&excl[dl8[i]], 1);        // LDS cursor claim
        o16[pos] = s16[i];
    }
    __syncthreads();
    for (int i = t; i < size; i += 256) colidx[lo + i] = o16[i];
}

// ---------------------------------------------------------------- attention projection vectors
__global__ __launch_bounds__(256) void attvec_k(const float* __restrict__ W,
                                                const float* __restrict__ att_s,
                                                const float* __restrict__ att_d,
                                                float* __restrict__ vsrc,
                                                float* __restrict__ vdst) {
    int t = threadIdx.x;
    int h = t >> 6, k = t & 63;
    float s_ = 0.f, d_ = 0.f;
#pragma unroll 8
    for (int c = 0; c < 64; c++) {
        float w = W[k * 256 + h * 64 + c];
        s_ += w * att_s[h * 64 + c];
        d_ += w * att_d[h * 64 + c];
    }
    vsrc[h * 64 + k] = s_;
    vdst[h * 64 + k] = d_;
}

// ---------------------------------------------------------------- GEMM1: h = fp16( dinv .* (x @ W_gcn) )
__global__ __launch_bounds__(256) void gemm1(const float* __restrict__ x,
                                             const float* __restrict__ W,
                                             const float* __restrict__ dinv,
                                             __half* __restrict__ h) {
    __shared__ float Wl[D_IN * HID];      // 8 KB
    int t = threadIdx.x;
    for (int i = t; i < D_IN * HID; i += 256) Wl[i] = W[i];
    __syncthreads();
    int c = t & 63, rw = t >> 6;
    int r0 = blockIdx.x * 32;
#pragma unroll
    for (int rr = 0; rr < 8; rr++) {
        int r = r0 + rr * 4 + rw;
        if (r >= N_NODES) break;
        const float4* xr4 = (const float4*)(x + r * D_IN);
        float acc = 0.f;
#pragma unroll
        for (int k4 = 0; k4 < D_IN / 4; k4++) {
            float4 xv = xr4[k4];
            int k = k4 * 4;
            acc += xv.x * Wl[(k+0)*HID + c] + xv.y * Wl[(k+1)*HID + c]
                 + xv.z * Wl[(k+2)*HID + c] + xv.w * Wl[(k+3)*HID + c];
        }
        h[r * HID + c] = __float2half(acc * dinv[r]);
    }
}

// ---------------------------------------------------------------- GCN aggregate -> h1 fp16 (relu), fused attention dots
// Octet layout: 8 lanes/edge, lane holds 8 channels (16B dwordx4); 8 edges/iter.
__global__ __launch_bounds__(256) void gcn_agg(const __half* __restrict__ h,
                                               const int* __restrict__ rowptr,
                                               const unsigned short* __restrict__ colidx,
                                               const float* __restrict__ dinv,
                                               const float* __restrict__ b,
                                               const float* __restrict__ vsrc,
                                               const float* __restrict__ vdst,
                                               __half* __restrict__ h1,
                                               float* __restrict__ as_o,
                                               float* __restrict__ ad_o) {
    __shared__ int sbuf[4][CHUNK + 8];
    int lane = threadIdx.x & 63, wv = threadIdx.x >> 6;
    int octet = lane >> 3, ol = lane & 7;
    int n = blockIdx.x * 4 + wv;
    if (n >= N_NODES) return;
    int rp = rowptr[n], re = rowptr[n + 1];
    f32x2 a0 = {0,0}, a1 = {0,0}, a2 = {0,0}, a3 = {0,0};
    const __half* hp = h + ol * 8;
    for (int cb = rp; cb < re; cb += CHUNK) {
        int ce = min(cb + CHUNK, re);
        for (int e = cb + lane; e < ce; e += 64) sbuf[wv][e - cb] = colidx[e];
        int m = ce - cb;
        int pad = (8 - (m & 7)) & 7;
        if (lane < pad) sbuf[wv][m + lane] = N_NODES;   // zero row
        int m8 = (m + pad) >> 3;
#pragma unroll 4
        for (int i = 0; i < m8; i++) {
            int s = sbuf[wv][i * 8 + octet];
            float4 raw = *(const float4*)(hp + s * HID);    // 8 fp16 = 16B
            float2 f0 = __half22float2(__builtin_bit_cast(__half2, raw.x));
            float2 f1 = __half22float2(__builtin_bit_cast(__half2, raw.y));
            float2 f2 = __half22float2(__builtin_bit_cast(__half2, raw.z));
            float2 f3 = __half22float2(__builtin_bit_cast(__half2, raw.w));
            a0.x += f0.x; a0.y += f0.y; a1.x += f1.x; a1.y += f1.y;
            a2.x += f2.x; a2.y += f2.y; a3.x += f3.x; a3.y += f3.y;
        }
    }
    // combine octets (xor 8, 16, 32)
#pragma unroll
    for (int off = 8; off <= 32; off <<= 1) {
        a0.x += __shfl_xor(a0.x, off); a0.y += __shfl_xor(a0.y, off);
        a1.x += __shfl_xor(a1.x, off); a1.y += __shfl_xor(a1.y, off);
        a2.x += __shfl_xor(a2.x, off); a2.y += __shfl_xor(a2.y, off);
        a3.x += __shfl_xor(a3.x, off); a3.y += __shfl_xor(a3.y, off);
    }
    // self-loop contribution (h pre-scaled by dinv[n]) — octet-0 lanes
    if (octet == 0) {
        float4 raw = *(const float4*)(hp + n * HID);
        float2 f0 = __half22float2(__builtin_bit_cast(__half2, raw.x));
        float2 f1 = __half22float2(__builtin_bit_cast(__half2, raw.y));
        float2 f2 = __half22float2(__builtin_bit_cast(__half2, raw.z));
        float2 f3 = __half22float2(__builtin_bit_cast(__half2, raw.w));
        a0.x += f0.x; a0.y += f0.y; a1.x += f1.x; a1.y += f1.y;
        a2.x += f2.x; a2.y += f2.y; a3.x += f3.x; a3.y += f3.y;
    }
    float dn = dinv[n];
    const float4 b0 = *(const float4*)&b[ol * 8];
    const float4 b1 = *(const float4*)&b[ol * 8 + 4];
    float v0 = fmaxf(a0.x * dn + b0.x, 0.f), v1 = fmaxf(a0.y * dn + b0.y, 0.f);
    float v2 = fmaxf(a1.x * dn + b0.z, 0.f), v3 = fmaxf(a1.y * dn + b0.w, 0.f);
    float v4 = fmaxf(a2.x * dn + b1.x, 0.f), v5 = fmaxf(a2.y * dn + b1.y, 0.f);
    float v6 = fmaxf(a3.x * dn + b1.z, 0.f), v7 = fmaxf(a3.y * dn + b1.w, 0.f);
    if (octet == 0) {
        __half2 o4[4] = {__floats2half2_rn(v0, v1), __floats2half2_rn(v2, v3),
                         __floats2half2_rn(v4, v5), __floats2half2_rn(v6, v7)};
        *(float4*)&h1[n * HID + ol * 8] = *(float4*)o4;   // 16B store
    }
    // attention dots (octet-0 lanes hold full sums; reduce within lanes 0-7)
#pragma unroll
    for (int hh = 0; hh < 4; hh++) {
        const float4 s0 = *(const float4*)&vsrc[hh * 64 + ol * 8];
        const float4 s1 = *(const float4*)&vsrc[hh * 64 + ol * 8 + 4];
        const float4 d0 = *(const float4*)&vdst[hh * 64 + ol * 8];
        const float4 d1 = *(const float4*)&vdst[hh * 64 + ol * 8 + 4];
        float vs = v0*s0.x + v1*s0.y + v2*s0.z + v3*s0.w + v4*s1.x + v5*s1.y + v6*s1.z + v7*s1.w;
        float vd = v0*d0.x + v1*d0.y + v2*d0.z + v3*d0.w + v4*d1.x + v5*d1.y + v6*d1.z + v7*d1.w;
#pragma unroll
        for (int off = 4; off > 0; off >>= 1) {
            vs += __shfl_xor(vs, off);
            vd += __shfl_xor(vd, off);
        }
        if (lane == 0) {
            as_o[n * 4 + hh] = vs;
            ad_o[n * 4 + hh] = vd;
        }
    }
}

// ---------------------------------------------------------------- GAT aggregate (no max pass; self-loop analytic) -> u fp16
// Octet layout: 8 lanes/edge, 16B dwordx4 loads, 8 edges/iter.
__global__ __launch_bounds__(256) void gat_agg(const __half* __restrict__ h1,
                                               const int* __restrict__ rowptr,
                                               const unsigned short* __restrict__ colidx,
                                               const float* __restrict__ a_s,
                                               const float* __restrict__ a_d,
                                               __half* __restrict__ u) {
    __shared__ float wbuf[4][(CHUNK + 8) * 4];
    __shared__ int   sbuf[4][CHUNK + 8];
    int lane = threadIdx.x & 63, wv = threadIdx.x >> 6;
    int octet = lane >> 3, ol = lane & 7;
    int n = blockIdx.x * 4 + wv;
    if (n >= N_NODES) return;
    int rp = rowptr[n], re = rowptr[n + 1];
    float4 ad4 = *(const float4*)&a_d[n * 4];
    float4 asn = *(const float4*)&a_s[n * 4];

    float dnx = 0.f, dny = 0.f, dnz = 0.f, dnw = 0.f;
    f32x2 acc[4][4];   // [head][channel-pair]
#pragma unroll
    for (int hh = 0; hh < 4; hh++)
#pragma unroll
        for (int c = 0; c < 4; c++) acc[hh][c] = (f32x2){0.f, 0.f};
    const __half* hp = h1 + ol * 8;
    for (int cb = rp; cb < re; cb += CHUNK) {
        int ce = min(cb + CHUNK, re);
        // phase B: distributed weights -> LDS
        for (int e = cb + lane; e < ce; e += 64) {
            int s = colidx[e];
            float4 a = *(const float4*)&a_s[s * 4];
            float vx = a.x + ad4.x; vx = fmaxf(vx, NEG_SLOPE * vx);
            float vy = a.y + ad4.y; vy = fmaxf(vy, NEG_SLOPE * vy);
            float vz = a.z + ad4.z; vz = fmaxf(vz, NEG_SLOPE * vz);
            float vw = a.w + ad4.w; vw = fmaxf(vw, NEG_SLOPE * vw);
            float wx = __expf(fminf(vx, 80.f)), wy = __expf(fminf(vy, 80.f));
            float wz = __expf(fminf(vz, 80.f)), ww = __expf(fminf(vw, 80.f));
            dnx += wx; dny += wy; dnz += wz; dnw += ww;
            int idx = e - cb;
            *(float4*)&wbuf[wv][idx * 4] = make_float4(wx, wy, wz, ww);
            sbuf[wv][idx] = s;
        }
        int m = ce - cb;
        int pad = (8 - (m & 7)) & 7;
        if (lane < pad) {
            sbuf[wv][m + lane] = N_NODES;
            *(float4*)&wbuf[wv][(m + lane) * 4] = make_float4(0.f, 0.f, 0.f, 0.f);
        }
        int m8 = (m + pad) >> 3;
        // phase C: 8 edges/iter, octet each, dwordx4 h1 loads; wbuf read is 8-way broadcast
#pragma unroll 4
        for (int i = 0; i < m8; i++) {
            int idx = i * 8 + octet;
            int s = sbuf[wv][idx];
            float4 w4 = *(const float4*)&wbuf[wv][idx * 4];
            float4 raw = *(const float4*)(hp + s * HID);
            float2 f0 = __half22float2(__builtin_bit_cast(__half2, raw.x));
            float2 f1 = __half22float2(__builtin_bit_cast(__half2, raw.y));
            float2 f2 = __half22float2(__builtin_bit_cast(__half2, raw.z));
            float2 f3 = __half22float2(__builtin_bit_cast(__half2, raw.w));
            f32x2 g0 = {f0.x, f0.y}, g1 = {f1.x, f1.y}, g2 = {f2.x, f2.y}, g3 = {f3.x, f3.y};
            f32x2 wx2 = {w4.x, w4.x}, wy2 = {w4.y, w4.y};
            f32x2 wz2 = {w4.z, w4.z}, ww2 = {w4.w, w4.w};
            acc[0][0] += wx2 * g0; acc[0][1] += wx2 * g1; acc[0][2] += wx2 * g2; acc[0][3] += wx2 * g3;
            acc[1][0] += wy2 * g0; acc[1][1] += wy2 * g1; acc[1][2] += wy2 * g2; acc[1][3] += wy2 * g3;
            acc[2][0] += wz2 * g0; acc[2][1] += wz2 * g1; acc[2][2] += wz2 * g2; acc[2][3] += wz2 * g3;
            acc[3][0] += ww2 * g0; acc[3][1] += ww2 * g1; acc[3][2] += ww2 * g2; acc[3][3] += ww2 * g3;
        }
    }
    // combine octets (xor 8, 16, 32)
#pragma unroll
    for (int hh = 0; hh < 4; hh++)
#pragma unroll
        for (int c = 0; c < 4; c++) {
#pragma unroll
            for (int off = 8; off <= 32; off <<= 1) {
                acc[hh][c].x += __shfl_xor(acc[hh][c].x, off);
                acc[hh][c].y += __shfl_xor(acc[hh][c].y, off);
            }
        }
    // reduce denominators
#pragma unroll
    for (int off = 32; off > 0; off >>= 1) {
        dnx += __shfl_xor(dnx, off);
        dny += __shfl_xor(dny, off);
        dnz += __shfl_xor(dnz, off);
        dnw += __shfl_xor(dnw, off);
    }
    // self-loop weights (wave-uniform)
    float sx = asn.x + ad4.x; sx = fmaxf(sx, NEG_SLOPE * sx);
    float sy = asn.y + ad4.y; sy = fmaxf(sy, NEG_SLOPE * sy);
    float sz = asn.z + ad4.z; sz = fmaxf(sz, NEG_SLOPE * sz);
    float sw = asn.w + ad4.w; sw = fmaxf(sw, NEG_SLOPE * sw);
    float wsx = __expf(fminf(sx, 80.f)), wsy = __expf(fminf(sy, 80.f));
    float wsz = __expf(fminf(sz, 80.f)), wsw = __expf(fminf(sw, 80.f));
    dnx += wsx; dny += wsy; dnz += wsz; dnw += wsw;
    if (octet == 0) {
        float4 raw = *(const float4*)(hp + n * HID);
        float2 f0 = __half22float2(__builtin_bit_cast(__half2, raw.x));
        float2 f1 = __half22float2(__builtin_bit_cast(__half2, raw.y));
        float2 f2 = __half22float2(__builtin_bit_cast(__half2, raw.z));
        float2 f3 = __half22float2(__builtin_bit_cast(__half2, raw.w));
        f32x2 g0 = {f0.x, f0.y}, g1 = {f1.x, f1.y}, g2 = {f2.x, f2.y}, g3 = {f3.x, f3.y};
        f32x2 wv4[4] = {{wsx, wsx}, {wsy, wsy}, {wsz, wsz}, {wsw, wsw}};
#pragma unroll
        for (int hh = 0; hh < 4; hh++) {
            acc[hh][0] += wv4[hh] * g0; acc[hh][1] += wv4[hh] * g1;
            acc[hh][2] += wv4[hh] * g2; acc[hh][3] += wv4[hh] * g3;
        }
        float r4[4] = {1.f / dnx, 1.f / dny, 1.f / dnz, 1.f / dnw};
#pragma unroll
        for (int hh = 0; hh < 4; hh++) {
            __half2 o4[4];
#pragma unroll
            for (int c = 0; c < 4; c++)
                o4[c] = __floats2half2_rn(acc[hh][c].x * r4[hh], acc[hh][c].y * r4[hh]);
            *(float4*)&u[n * 256 + hh * 64 + ol * 8] = *(float4*)o4;   // 16B store
        }
    }
}

// ---------------------------------------------------------------- gemm2b (MFMA): h2 = fp16 relu(u @ blockdiag(W_gat) + b)
__global__ __launch_bounds__(256) void gemm2b(const __half* __restrict__ u,
                                              const float* __restrict__ W,
                                              const float* __restrict__ b,
                                              __half* __restrict__ h2) {
    int lane = threadIdx.x & 63, hd = threadIdx.x >> 6;
    int quad = lane >> 4, l16 = lane & 15;
    half8 Bf[4][2];
#pragma unroll
    for (int nt = 0; nt < 4; nt++)
#pragma unroll
        for (int kc = 0; kc < 2; kc++) {
            const float* wp = W + (kc * 32 + quad * 8) * 256 + hd * 64 + nt * 16 + l16;
#pragma unroll
            for (int j = 0; j < 8; j++)
                Bf[nt][kc][j] = (_Float16)wp[j * 256];
        }
    float bb[4];
#pragma unroll
    for (int nt = 0; nt < 4; nt++) bb[nt] = b[hd * 64 + nt * 16 + l16];

    int rt0 = blockIdx.x * 5;
#pragma unroll
    for (int i = 0; i < 5; i++) {
        int rt = rt0 + i;
        const __half* up = u + ((size_t)(rt * 16 + l16)) * 256 + hd * 64 + quad * 8;
        half8 A0 = *(const half8*)(const void*)up;
        half8 A1 = *(const half8*)(const void*)(up + 32);
        f32x4 acc[4];
#pragma unroll
        for (int nt = 0; nt < 4; nt++) {
            acc[nt] = (f32x4){0.f, 0.f, 0.f, 0.f};
            acc[nt] = __builtin_amdgcn_mfma_f32_16x16x32_f16(A0, Bf[nt][0], acc[nt], 0, 0, 0);
            acc[nt] = __builtin_amdgcn_mfma_f32_16x16x32_f16(A1, Bf[nt][1], acc[nt], 0, 0, 0);
        }
#pragma unroll
        for (int nt = 0; nt < 4; nt++) {
            int col = hd * 64 + nt * 16 + l16;
#pragma unroll
            for (int reg = 0; reg < 4; reg++) {
                int row = rt * 16 + quad * 4 + reg;
                h2[(size_t)row * 256 + col] = __float2half(fmaxf(acc[nt][reg] + bb[nt], 0.f));
            }
        }
    }
}

// ---------------------------------------------------------------- gemm3 (MFMA): out = h2 @ W_fc + b_fc
__global__ __launch_bounds__(256) void gemm3(const __half* __restrict__ h2,
                                             const float* __restrict__ W,
                                             const float* __restrict__ b,
                                             float* __restrict__ out) {
    int lane = threadIdx.x & 63, wv = threadIdx.x >> 6;
    int quad = lane >> 4, l16 = lane & 15;
    half8 Bf[2][8];
#pragma unroll
    for (int nt = 0; nt < 2; nt++)
#pragma unroll
        for (int kc = 0; kc < 8; kc++) {
            const float* wp = W + (kc * 32 + quad * 8) * 32 + nt * 16 + l16;
#pragma unroll
            for (int j = 0; j < 8; j++)
                Bf[nt][kc][j] = (_Float16)wp[j * 32];
        }
    float bb0 = b[l16], bb1 = b[16 + l16];

    for (int tile = blockIdx.x * 4 + wv; tile < NTILES; tile += gridDim.x * 4) {
        const __half* hp = h2 + (size_t)(tile * 16 + l16) * 256 + quad * 8;
        f32x4 acc0 = {0.f, 0.f, 0.f, 0.f};
        f32x4 acc1 = {0.f, 0.f, 0.f, 0.f};
#pragma unroll
        for (int kc = 0; kc < 8; kc++) {
            half8 A = *(const half8*)(const void*)(hp + kc * 32);
            acc0 = __builtin_amdgcn_mfma_f32_16x16x32_f16(A, Bf[0][kc], acc0, 0, 0, 0);
            acc1 = __builtin_amdgcn_mfma_f32_16x16x32_f16(A, Bf[1][kc], acc1, 0, 0, 0);
        }
#pragma unroll
        for (int reg = 0; reg < 4; reg++) {
            int row = tile * 16 + quad * 4 + reg;
            out[row * 32 + l16]      = acc0[reg] + bb0;
            out[row * 32 + 16 + l16] = acc1[reg] + bb1;
        }
    }
}

// ---------------------------------------------------------------- launch
extern "C" void kernel_launch(void* const* d_in, const int* in_sizes, int n_in,
                              void* d_out, int out_size, void* d_ws, size_t ws_size,
                              hipStream_t stream) {
    const float* x      = (const float*)d_in[0];
    const int*   edge   = (const int*)  d_in[1];
    const float* W_gcn  = (const float*)d_in[2];
    const float* b_gcn  = (const float*)d_in[3];
    const float* W_gat  = (const float*)d_in[4];
    const float* att_s  = (const float*)d_in[5];
    const float* att_d  = (const float*)d_in[6];
    const float* b_gat  = (const float*)d_in[7];
    const float* W_fc   = (const float*)d_in[8];
    const float* b_fc   = (const float*)d_in[9];
    float* out = (float*)d_out;

    char* p = (char*)d_ws;
    auto alloc = [&](size_t bytes) {
        char* q = p;
        p += (bytes + 255) & ~(size_t)255;
        return q;
    };
    __half* h     = (__half*)alloc((size_t)(N_NODES + 1) * HID * 2);   // +1 zero row
    __half* h1    = (__half*)alloc((size_t)(N_NODES + 1) * HID * 2);   // +1 zero row
    __half* u     = (__half*)alloc((size_t)N_NODES * 256 * 2);
    __half* h2    = (__half*)alloc((size_t)N_NODES * 256 * 2);
    float* as_a   = (float*)alloc((size_t)N_NODES * 4 * 4);
    float* ad_a   = (float*)alloc((size_t)N_NODES * 4 * 4);
    float* dinv   = (float*)alloc((size_t)N_NODES * 4);
    int*   rowptr = (int*)  alloc((size_t)(N_NODES + 1) * 4);
    unsigned short* colidx = (unsigned short*)alloc((size_t)N_EDGES * 2);
    int*   ghist  = (int*)  alloc((size_t)GH * 4);
    int*   bsum   = (int*)  alloc((size_t)NSB * 4);
    unsigned* tmp = (unsigned*)alloc((size_t)N_EDGES * 4);
    float* vsrc   = (float*)alloc((size_t)HEADS * HID * 4);
    float* vdst   = (float*)alloc((size_t)HEADS * HID * 4);

    // zero the padding rows (index N_NODES used by pad lanes)
    hipMemsetAsync(h  + (size_t)N_NODES * HID, 0, HID * 2, stream);
    hipMemsetAsync(h1 + (size_t)N_NODES * HID, 0, HID * 2, stream);

    // CSR build: atomic-free MSD bucket sort (hierarchical coalesced scan)
    histA   <<<NBLK_A, 256, 0, stream>>>(edge, ghist);
    scanB1  <<<NSB, 256, 0, stream>>>(ghist, bsum);
    scanB2  <<<1, 320, 0, stream>>>(bsum);
    scanB3  <<<NSB, 256, 0, stream>>>(ghist, bsum);
    scatterC<<<NBLK_A, 256, 0, stream>>>(edge, ghist, tmp);
    sortD   <<<NBKT, 256, 0, stream>>>(tmp, ghist, colidx, rowptr, dinv);

    // attention projection vectors
    attvec_k<<<1, 256, 0, stream>>>(W_gat, att_s, att_d, vsrc, vdst);

    // GCN
    gemm1   <<<(N_NODES + 31) / 32, 256, 0, stream>>>(x, W_gcn, dinv, h);
    gcn_agg <<<(N_NODES + 3) / 4, 256, 0, stream>>>(h, rowptr, colidx, dinv, b_gcn,
                                                    vsrc, vdst, h1, as_a, ad_a);

    // GAT
    gat_agg <<<(N_NODES + 3) / 4, 256, 0, stream>>>(h1, rowptr, colidx, as_a, ad_a, u);
    gemm2b  <<<625, 256, 0, stream>>>(u, W_gat, b_gat, h2);

    // FC
    gemm3   <<<256, 256, 0, stream>>>(h2, W_fc, b_fc, out);
}

// Round 13
// 263.458 us; speedup vs baseline: 1.0878x; 1.0878x over previous
//
#include <hip/hip_runtime.h>
#include <hip/hip_bf16.h>
#include <hip/hip_fp16.h>
#include <math.h>

#define N_NODES 50000
#define N_EDGES 1600000
#define D_IN    32
#define HID     64
#define HEADS   4
#define D_OUT   32
#define NEG_SLOPE 0.2f
#define CHUNK 128
#define NTILES 3125   // N_NODES / 16, exact

// MSD bucket-sort CSR build
#define NBKT 196      // d>>8 buckets (d < 50000)
#define NBLK_A 391    // ceil(1.6M / 4096)
#define TILE_A 4096
#define GH (NBKT * NBLK_A)   // 76636
#define NSB 300       // ceil(GH / 256)
#define CAP 10240     // max bucket size (avg 8163, sigma ~90 -> 23 sigma margin)

typedef _Float16 half8 __attribute__((ext_vector_type(8)));
typedef float    f32x4 __attribute__((ext_vector_type(4)));
typedef float    f32x2 __attribute__((ext_vector_type(2)));

// ---------------------------------------------------------------- CSR: pass A — per-block 196-bin histogram (LDS, per-wave replicas)
__global__ __launch_bounds__(256) void histA(const int* __restrict__ edge,
                                             int* __restrict__ ghist) {
    __shared__ int hist[4][NBKT];
    int t = threadIdx.x, wv = t >> 6;
    for (int i = t; i < 4 * NBKT; i += 256) ((int*)hist)[i] = 0;
    __syncthreads();
    int base = blockIdx.x * TILE_A;
#pragma unroll
    for (int k = 0; k < 16; k++) {
        int i = base + k * 256 + t;
        if (i < N_EDGES) atomicAdd(&hist[wv][edge[N_EDGES + i] >> 8], 1);
    }
    __syncthreads();
    for (int b = t; b < NBKT; b += 256)
        ghist[b * NBLK_A + blockIdx.x] = hist[0][b] + hist[1][b] + hist[2][b] + hist[3][b];
}

// ---------------------------------------------------------------- CSR: pass B — hierarchical coalesced scan of GH entries
__global__ __launch_bounds__(256) void scanB1(const int* __restrict__ g,
                                              int* __restrict__ bsum) {
    int t = threadIdx.x;
    int i = blockIdx.x * 256 + t;
    int v = (i < GH) ? g[i] : 0;              // coalesced
#pragma unroll
    for (int off = 32; off; off >>= 1) v += __shfl_xor(v, off);
    __shared__ int ws[4];
    if ((t & 63) == 0) ws[t >> 6] = v;
    __syncthreads();
    if (t == 0) bsum[blockIdx.x] = ws[0] + ws[1] + ws[2] + ws[3];
}

__global__ __launch_bounds__(320) void scanB2(int* __restrict__ bsum) {
    int t = threadIdx.x, lane = t & 63, wv = t >> 6;
    int v = (t < NSB) ? bsum[t] : 0;
    int inc = v;
#pragma unroll
    for (int d = 1; d < 64; d <<= 1) {
        int u = __shfl_up(inc, d);
        if (lane >= d) inc += u;
    }
    __shared__ int ws[5];
    if (lane == 63) ws[wv] = inc;
    __syncthreads();
    int add = 0;
#pragma unroll
    for (int j = 0; j < 5; j++) if (j < wv) add += ws[j];
    if (t < NSB) bsum[t] = add + inc - v;     // exclusive block offsets
}

__global__ __launch_bounds__(256) void scanB3(int* __restrict__ g,
                                              const int* __restrict__ bsum) {
    int t = threadIdx.x, lane = t & 63, wv = t >> 6;
    int i = blockIdx.x * 256 + t;
    int v = (i < GH) ? g[i] : 0;              // coalesced
    int inc = v;
#pragma unroll
    for (int d = 1; d < 64; d <<= 1) {
        int u = __shfl_up(inc, d);
        if (lane >= d) inc += u;
    }
    __shared__ int ws[4];
    if (lane == 63) ws[wv] = inc;
    __syncthreads();
    int add = 0;
#pragma unroll
    for (int j = 0; j < 4; j++) if (j < wv) add += ws[j];
    if (i < GH) g[i] = bsum[blockIdx.x] + add + inc - v;   // exclusive prefix
}

// ---------------------------------------------------------------- CSR: pass C — scatter packed (d<<16|s) via LDS cursors (disjoint global ranges)
__global__ __launch_bounds__(256) void scatterC(const int* __restrict__ edge,
                                                const int* __restrict__ ghist,
                                                unsigned* __restrict__ tmp) {
    __shared__ int cur[NBKT];
    int t = threadIdx.x;
    if (t < NBKT) cur[t] = ghist[t * NBLK_A + blockIdx.x];
    __syncthreads();
    int base = blockIdx.x * TILE_A;
#pragma unroll
    for (int k = 0; k < 16; k++) {
        int i = base + k * 256 + t;
        if (i < N_EDGES) {
            int s = edge[i], d = edge[N_EDGES + i];
            int pos = atomicAdd(&cur[d >> 8], 1);     // LDS atomic
            tmp[pos] = ((unsigned)d << 16) | (unsigned)s;
        }
    }
}

// ---------------------------------------------------------------- CSR: pass D — per-bucket 256-bin regroup; emits colidx(u16), rowptr, dinv
__global__ __launch_bounds__(256) void sortD(const unsigned* __restrict__ tmp,
                                             const int* __restrict__ ghist,
                                             unsigned short* __restrict__ colidx,
                                             int* __restrict__ rowptr,
                                             float* __restrict__ dinv) {
    __shared__ unsigned char  dl8[CAP];
    __shared__ unsigned short s16[CAP];
    __shared__ unsigned short o16[CAP];
    __shared__ int hist[4][256];
    __shared__ int excl[256];
    __shared__ int wsum[4];
    int t = threadIdx.x, lane = t & 63, wv = t >> 6;
    int b = blockIdx.x;
    int lo = ghist[b * NBLK_A];
    int hi = (b < NBKT - 1) ? ghist[(b + 1) * NBLK_A] : N_EDGES;
    int size = hi - lo;
    if (size > CAP) size = CAP;           // unreachable safety clamp
    for (int i = t; i < 4 * 256; i += 256) ((int*)hist)[i] = 0;
    __syncthreads();
    for (int i = t; i < size; i += 256) {
        unsigned key = tmp[lo + i];
        int dl = (key >> 16) & 255;
        dl8[i] = (unsigned char)dl;
        s16[i] = (unsigned short)(key & 0xFFFF);
        atomicAdd(&hist[wv][dl], 1);
    }
    __syncthreads();
    int h = hist[0][t] + hist[1][t] + hist[2][t] + hist[3][t];
    int inc = h;
#pragma unroll
    for (int d = 1; d < 64; d <<= 1) {
        int u = __shfl_up(inc, d);
        if (lane >= d) inc += u;
    }
    if (lane == 63) wsum[wv] = inc;
    __syncthreads();
    int add = 0;
#pragma unroll
    for (int j = 0; j < 4; j++) if (j < wv) add += wsum[j];
    int ex = inc - h + add;
    excl[t] = ex;
    int node = b * 256 + t;
    if (node < N_NODES) {
        rowptr[node] = lo + ex;
        dinv[node]   = rsqrtf((float)(h + 1));        // +1 self-loop
    }
    if (b == NBKT - 1 && t == 0) rowptr[N_NODES] = N_EDGES;
    __syncthreads();
    for (int i = t; i < size; i += 256) {
        int pos = atomicAdd(&excl[dl8[i]], 1);        // LDS cursor claim
        o16[pos] = s16[i];
    }
    __syncthreads();
    for (int i = t; i < size; i += 256) colidx[lo + i] = o16[i];
}

// ---------------------------------------------------------------- attention projection vectors
__global__ __launch_bounds__(256) void attvec_k(const float* __restrict__ W,
                                                const float* __restrict__ att_s,
                                                const float* __restrict__ att_d,
                                                float* __restrict__ vsrc,
                                                float* __restrict__ vdst) {
    int t = threadIdx.x;
    int h = t >> 6, k = t & 63;
    float s_ = 0.f, d_ = 0.f;
#pragma unroll 8
    for (int c = 0; c < 64; c++) {
        float w = W[k * 256 + h * 64 + c];
        s_ += w * att_s[h * 64 + c];
        d_ += w * att_d[h * 64 + c];
    }
    vsrc[h * 64 + k] = s_;
    vdst[h * 64 + k] = d_;
}

// ---------------------------------------------------------------- GEMM1: h = fp16( dinv .* (x @ W_gcn) )
__global__ __launch_bounds__(256) void gemm1(const float* __restrict__ x,
                                             const float* __restrict__ W,
                                             const float* __restrict__ dinv,
                                             __half* __restrict__ h) {
    __shared__ float Wl[D_IN * HID];      // 8 KB
    int t = threadIdx.x;
    for (int i = t; i < D_IN * HID; i += 256) Wl[i] = W[i];
    __syncthreads();
    int c = t & 63, rw = t >> 6;
    int r0 = blockIdx.x * 32;
#pragma unroll
    for (int rr = 0; rr < 8; rr++) {
        int r = r0 + rr * 4 + rw;
        if (r >= N_NODES) break;
        const float4* xr4 = (const float4*)(x + r * D_IN);
        float acc = 0.f;
#pragma unroll
        for (int k4 = 0; k4 < D_IN / 4; k4++) {
            float4 xv = xr4[k4];
            int k = k4 * 4;
            acc += xv.x * Wl[(k+0)*HID + c] + xv.y * Wl[(k+1)*HID + c]
                 + xv.z * Wl[(k+2)*HID + c] + xv.w * Wl[(k+3)*HID + c];
        }
        h[r * HID + c] = __float2half(acc * dinv[r]);
    }
}

// ---------------------------------------------------------------- GCN aggregate -> h1 fp16 (relu), fused attention dots
// Quarter layout (R11): 16 lanes/edge, lane holds 4 channels (8B dwordx2); 4 edges/iter.
__global__ __launch_bounds__(256) void gcn_agg(const __half* __restrict__ h,
                                               const int* __restrict__ rowptr,
                                               const unsigned short* __restrict__ colidx,
                                               const float* __restrict__ dinv,
                                               const float* __restrict__ b,
                                               const float* __restrict__ vsrc,
                                               const float* __restrict__ vdst,
                                               __half* __restrict__ h1,
                                               float* __restrict__ as_o,
                                               float* __restrict__ ad_o) {
    __shared__ int sbuf[4][CHUNK + 4];
    int lane = threadIdx.x & 63, wv = threadIdx.x >> 6;
    int quarter = lane >> 4, ql = lane & 15;
    int n = blockIdx.x * 4 + wv;
    if (n >= N_NODES) return;
    int rp = rowptr[n], re = rowptr[n + 1];
    f32x2 a01 = {0.f, 0.f}, a23 = {0.f, 0.f};
    const __half* hp = h + ql * 4;
    for (int cb = rp; cb < re; cb += CHUNK) {
        int ce = min(cb + CHUNK, re);
        for (int e = cb + lane; e < ce; e += 64) sbuf[wv][e - cb] = colidx[e];
        int m = ce - cb;
        int pad = (4 - (m & 3)) & 3;
        if (lane < pad) sbuf[wv][m + lane] = N_NODES;   // zero row
        int m4 = (m + pad) >> 2;
#pragma unroll 4
        for (int i = 0; i < m4; i++) {
            int s = sbuf[wv][i * 4 + quarter];
            float2 raw = *(const float2*)(hp + s * HID);    // 4 fp16
            __half2 g0 = __builtin_bit_cast(__half2, raw.x);
            __half2 g1 = __builtin_bit_cast(__half2, raw.y);
            float2 f0 = __half22float2(g0), f1 = __half22float2(g1);
            a01.x += f0.x; a01.y += f0.y;
            a23.x += f1.x; a23.y += f1.y;
        }
    }
    // combine quarters (xor 16, 32)
#pragma unroll
    for (int off = 16; off <= 32; off <<= 1) {
        a01.x += __shfl_xor(a01.x, off); a01.y += __shfl_xor(a01.y, off);
        a23.x += __shfl_xor(a23.x, off); a23.y += __shfl_xor(a23.y, off);
    }
    // self-loop contribution (h pre-scaled by dinv[n]) — quarter-0 lanes only
    if (quarter == 0) {
        float2 raw = *(const float2*)(hp + n * HID);
        __half2 g0 = __builtin_bit_cast(__half2, raw.x);
        __half2 g1 = __builtin_bit_cast(__half2, raw.y);
        float2 f0 = __half22float2(g0), f1 = __half22float2(g1);
        a01.x += f0.x; a01.y += f0.y;
        a23.x += f1.x; a23.y += f1.y;
    }
    float dn = dinv[n];
    const float4 bb = *(const float4*)&b[ql * 4];
    float v0 = fmaxf(a01.x * dn + bb.x, 0.f);
    float v1 = fmaxf(a01.y * dn + bb.y, 0.f);
    float v2 = fmaxf(a23.x * dn + bb.z, 0.f);
    float v3 = fmaxf(a23.y * dn + bb.w, 0.f);
    if (quarter == 0) {
        __half2* op = (__half2*)&h1[n * HID + ql * 4];
        op[0] = __floats2half2_rn(v0, v1);
        op[1] = __floats2half2_rn(v2, v3);
    }
    // attention dots (quarter-0 values feed lane 0's write)
#pragma unroll
    for (int hh = 0; hh < 4; hh++) {
        float4 vsp = *(const float4*)&vsrc[hh * 64 + ql * 4];
        float4 vdp = *(const float4*)&vdst[hh * 64 + ql * 4];
        float vs = v0 * vsp.x + v1 * vsp.y + v2 * vsp.z + v3 * vsp.w;
        float vd = v0 * vdp.x + v1 * vdp.y + v2 * vdp.z + v3 * vdp.w;
#pragma unroll
        for (int off = 8; off > 0; off >>= 1) {
            vs += __shfl_xor(vs, off);
            vd += __shfl_xor(vd, off);
        }
        if (lane == 0) {
            as_o[n * 4 + hh] = vs;
            ad_o[n * 4 + hh] = vd;
        }
    }
}

// ---------------------------------------------------------------- GAT aggregate (no max pass; self-loop analytic) -> u fp16
// Quarter layout (R11): 16 lanes/edge, 8B dwordx2 loads, 4 edges/iter.
__global__ __launch_bounds__(256) void gat_agg(const __half* __restrict__ h1,
                                               const int* __restrict__ rowptr,
                                               const unsigned short* __restrict__ colidx,
                                               const float* __restrict__ a_s,
                                               const float* __restrict__ a_d,
                                               __half* __restrict__ u) {
    __shared__ float wbuf[4][(CHUNK + 4) * 4];
    __shared__ int   sbuf[4][CHUNK + 4];
    int lane = threadIdx.x & 63, wv = threadIdx.x >> 6;
    int quarter = lane >> 4, ql = lane & 15;
    int n = blockIdx.x * 4 + wv;
    if (n >= N_NODES) return;
    int rp = rowptr[n], re = rowptr[n + 1];
    float4 ad4 = *(const float4*)&a_d[n * 4];
    float4 asn = *(const float4*)&a_s[n * 4];

    float dnx = 0.f, dny = 0.f, dnz = 0.f, dnw = 0.f;
    f32x2 acc[4][2];
#pragma unroll
    for (int hh = 0; hh < 4; hh++) { acc[hh][0] = (f32x2){0.f,0.f}; acc[hh][1] = (f32x2){0.f,0.f}; }
    const __half* hp = h1 + ql * 4;
    for (int cb = rp; cb < re; cb += CHUNK) {
        int ce = min(cb + CHUNK, re);
        // phase B: distributed weights -> LDS
        for (int e = cb + lane; e < ce; e += 64) {
            int s = colidx[e];
            float4 a = *(const float4*)&a_s[s * 4];
            float vx = a.x + ad4.x; vx = fmaxf(vx, NEG_SLOPE * vx);
            float vy = a.y + ad4.y; vy = fmaxf(vy, NEG_SLOPE * vy);
            float vz = a.z + ad4.z; vz = fmaxf(vz, NEG_SLOPE * vz);
            float vw = a.w + ad4.w; vw = fmaxf(vw, NEG_SLOPE * vw);
            float wx = __expf(fminf(vx, 80.f)), wy = __expf(fminf(vy, 80.f));
            float wz = __expf(fminf(vz, 80.f)), ww = __expf(fminf(vw, 80.f));
            dnx += wx; dny += wy; dnz += wz; dnw += ww;
            int idx = e - cb;
            *(float4*)&wbuf[wv][idx * 4] = make_float4(wx, wy, wz, ww);
            sbuf[wv][idx] = s;
        }
        int m = ce - cb;
        int pad = (4 - (m & 3)) & 3;
        if (lane < pad) {
            sbuf[wv][m + lane] = N_NODES;
            *(float4*)&wbuf[wv][(m + lane) * 4] = make_float4(0.f, 0.f, 0.f, 0.f);
        }
        int m4 = (m + pad) >> 2;
#pragma unroll 4
        for (int i = 0; i < m4; i++) {
            int idx = i * 4 + quarter;
            int s = sbuf[wv][idx];
            float4 w4 = *(const float4*)&wbuf[wv][idx * 4];
            float2 raw = *(const float2*)(hp + s * HID);
            __half2 g0 = __builtin_bit_cast(__half2, raw.x);
            __half2 g1 = __builtin_bit_cast(__half2, raw.y);
            float2 t0 = __half22float2(g0), t1 = __half22float2(g1);
            f32x2 f0 = {t0.x, t0.y}, f1 = {t1.x, t1.y};
            f32x2 wx2 = {w4.x, w4.x}, wy2 = {w4.y, w4.y};
            f32x2 wz2 = {w4.z, w4.z}, ww2 = {w4.w, w4.w};
            acc[0][0] += wx2 * f0; acc[0][1] += wx2 * f1;
            acc[1][0] += wy2 * f0; acc[1][1] += wy2 * f1;
            acc[2][0] += wz2 * f0; acc[2][1] += wz2 * f1;
            acc[3][0] += ww2 * f0; acc[3][1] += ww2 * f1;
        }
    }
    // combine quarters
#pragma unroll
    for (int hh = 0; hh < 4; hh++)
#pragma unroll
        for (int c = 0; c < 2; c++) {
            acc[hh][c].x += __shfl_xor(acc[hh][c].x, 16);
            acc[hh][c].y += __shfl_xor(acc[hh][c].y, 16);
            acc[hh][c].x += __shfl_xor(acc[hh][c].x, 32);
            acc[hh][c].y += __shfl_xor(acc[hh][c].y, 32);
        }
    // reduce denominators
#pragma unroll
    for (int off = 32; off > 0; off >>= 1) {
        dnx += __shfl_xor(dnx, off);
        dny += __shfl_xor(dny, off);
        dnz += __shfl_xor(dnz, off);
        dnw += __shfl_xor(dnw, off);
    }
    // self-loop: w_self per head (wave-uniform)
    float sx = asn.x + ad4.x; sx = fmaxf(sx, NEG_SLOPE * sx);
    float sy = asn.y + ad4.y; sy = fmaxf(sy, NEG_SLOPE * sy);
    float sz = asn.z + ad4.z; sz = fmaxf(sz, NEG_SLOPE * sz);
    float sw = asn.w + ad4.w; sw = fmaxf(sw, NEG_SLOPE * sw);
    float wsx = __expf(fminf(sx, 80.f)), wsy = __expf(fminf(sy, 80.f));
    float wsz = __expf(fminf(sz, 80.f)), wsw = __expf(fminf(sw, 80.f));
    dnx += wsx; dny += wsy; dnz += wsz; dnw += wsw;
    if (quarter == 0) {
        float2 raw = *(const float2*)(hp + n * HID);
        __half2 g0 = __builtin_bit_cast(__half2, raw.x);
        __half2 g1 = __builtin_bit_cast(__half2, raw.y);
        float2 t0 = __half22float2(g0), t1 = __half22float2(g1);
        acc[0][0].x += wsx * t0.x; acc[0][0].y += wsx * t0.y; acc[0][1].x += wsx * t1.x; acc[0][1].y += wsx * t1.y;
        acc[1][0].x += wsy * t0.x; acc[1][0].y += wsy * t0.y; acc[1][1].x += wsy * t1.x; acc[1][1].y += wsy * t1.y;
        acc[2][0].x += wsz * t0.x; acc[2][0].y += wsz * t0.y; acc[2][1].x += wsz * t1.x; acc[2][1].y += wsz * t1.y;
        acc[3][0].x += wsw * t0.x; acc[3][0].y += wsw * t0.y; acc[3][1].x += wsw * t1.x; acc[3][1].y += wsw * t1.y;
        float r4[4] = {1.f / dnx, 1.f / dny, 1.f / dnz, 1.f / dnw};
        __half* up = u + n * 256 + ql * 4;
#pragma unroll
        for (int hh = 0; hh < 4; hh++) {
            __half2* op = (__half2*)&up[hh * 64];
            op[0] = __floats2half2_rn(acc[hh][0].x * r4[hh], acc[hh][0].y * r4[hh]);
            op[1] = __floats2half2_rn(acc[hh][1].x * r4[hh], acc[hh][1].y * r4[hh]);
        }
    }
}

// ---------------------------------------------------------------- gemm2b (MFMA): h2 = fp16 relu(u @ blockdiag(W_gat) + b)
__global__ __launch_bounds__(256) void gemm2b(const __half* __restrict__ u,
                                              const float* __restrict__ W,
                                              const float* __restrict__ b,
                                              __half* __restrict__ h2) {
    int lane = threadIdx.x & 63, hd = threadIdx.x >> 6;
    int quad = lane >> 4, l16 = lane & 15;
    half8 Bf[4][2];
#pragma unroll
    for (int nt = 0; nt < 4; nt++)
#pragma unroll
        for (int kc = 0; kc < 2; kc++) {
            const float* wp = W + (kc * 32 + quad * 8) * 256 + hd * 64 + nt * 16 + l16;
#pragma unroll
            for (int j = 0; j < 8; j++)
                Bf[nt][kc][j] = (_Float16)wp[j * 256];
        }
    float bb[4];
#pragma unroll
    for (int nt = 0; nt < 4; nt++) bb[nt] = b[hd * 64 + nt * 16 + l16];

    int rt0 = blockIdx.x * 5;
#pragma unroll
    for (int i = 0; i < 5; i++) {
        int rt = rt0 + i;
        const __half* up = u + ((size_t)(rt * 16 + l16)) * 256 + hd * 64 + quad * 8;
        half8 A0 = *(const half8*)(const void*)up;
        half8 A1 = *(const half8*)(const void*)(up + 32);
        f32x4 acc[4];
#pragma unroll
        for (int nt = 0; nt < 4; nt++) {
            acc[nt] = (f32x4){0.f, 0.f, 0.f, 0.f};
            acc[nt] = __builtin_amdgcn_mfma_f32_16x16x32_f16(A0, Bf[nt][0], acc[nt], 0, 0, 0);
            acc[nt] = __builtin_amdgcn_mfma_f32_16x16x32_f16(A1, Bf[nt][1], acc[nt], 0, 0, 0);
        }
#pragma unroll
        for (int nt = 0; nt < 4; nt++) {
            int col = hd * 64 + nt * 16 + l16;
#pragma unroll
            for (int reg = 0; reg < 4; reg++) {
                int row = rt * 16 + quad * 4 + reg;
                h2[(size_t)row * 256 + col] = __float2half(fmaxf(acc[nt][reg] + bb[nt], 0.f));
            }
        }
    }
}

// ---------------------------------------------------------------- gemm3 (MFMA): out = h2 @ W_fc + b_fc
__global__ __launch_bounds__(256) void gemm3(const __half* __restrict__ h2,
                                             const float* __restrict__ W,
                                             const float* __restrict__ b,
                                             float* __restrict__ out) {
    int lane = threadIdx.x & 63, wv = threadIdx.x >> 6;
    int quad = lane >> 4, l16 = lane & 15;
    half8 Bf[2][8];
#pragma unroll
    for (int nt = 0; nt < 2; nt++)
#pragma unroll
        for (int kc = 0; kc < 8; kc++) {
            const float* wp = W + (kc * 32 + quad * 8) * 32 + nt * 16 + l16;
#pragma unroll
            for (int j = 0; j < 8; j++)
                Bf[nt][kc][j] = (_Float16)wp[j * 32];
        }
    float bb0 = b[l16], bb1 = b[16 + l16];

    for (int tile = blockIdx.x * 4 + wv; tile < NTILES; tile += gridDim.x * 4) {
        const __half* hp = h2 + (size_t)(tile * 16 + l16) * 256 + quad * 8;
        f32x4 acc0 = {0.f, 0.f, 0.f, 0.f};
        f32x4 acc1 = {0.f, 0.f, 0.f, 0.f};
#pragma unroll
        for (int kc = 0; kc < 8; kc++) {
            half8 A = *(const half8*)(const void*)(hp + kc * 32);
            acc0 = __builtin_amdgcn_mfma_f32_16x16x32_f16(A, Bf[0][kc], acc0, 0, 0, 0);
            acc1 = __builtin_amdgcn_mfma_f32_16x16x32_f16(A, Bf[1][kc], acc1, 0, 0, 0);
        }
#pragma unroll
        for (int reg = 0; reg < 4; reg++) {
            int row = tile * 16 + quad * 4 + reg;
            out[row * 32 + l16]      = acc0[reg] + bb0;
            out[row * 32 + 16 + l16] = acc1[reg] + bb1;
        }
    }
}

// ---------------------------------------------------------------- launch
extern "C" void kernel_launch(void* const* d_in, const int* in_sizes, int n_in,
                              void* d_out, int out_size, void* d_ws, size_t ws_size,
                              hipStream_t stream) {
    const float* x      = (const float*)d_in[0];
    const int*   edge   = (const int*)  d_in[1];
    const float* W_gcn  = (const float*)d_in[2];
    const float* b_gcn  = (const float*)d_in[3];
    const float* W_gat  = (const float*)d_in[4];
    const float* att_s  = (const float*)d_in[5];
    const float* att_d  = (const float*)d_in[6];
    const float* b_gat  = (const float*)d_in[7];
    const float* W_fc   = (const float*)d_in[8];
    const float* b_fc   = (const float*)d_in[9];
    float* out = (float*)d_out;

    char* p = (char*)d_ws;
    auto alloc = [&](size_t bytes) {
        char* q = p;
        p += (bytes + 255) & ~(size_t)255;
        return q;
    };
    __half* h     = (__half*)alloc((size_t)(N_NODES + 1) * HID * 2);   // +1 zero row
    __half* h1    = (__half*)alloc((size_t)(N_NODES + 1) * HID * 2);   // +1 zero row
    __half* u     = (__half*)alloc((size_t)N_NODES * 256 * 2);
    __half* h2    = (__half*)alloc((size_t)N_NODES * 256 * 2);
    float* as_a   = (float*)alloc((size_t)N_NODES * 4 * 4);
    float* ad_a   = (float*)alloc((size_t)N_NODES * 4 * 4);
    float* dinv   = (float*)alloc((size_t)N_NODES * 4);
    int*   rowptr = (int*)  alloc((size_t)(N_NODES + 1) * 4);
    unsigned short* colidx = (unsigned short*)alloc((size_t)N_EDGES * 2);
    int*   ghist  = (int*)  alloc((size_t)GH * 4);
    int*   bsum   = (int*)  alloc((size_t)NSB * 4);
    unsigned* tmp = (unsigned*)alloc((size_t)N_EDGES * 4);
    float* vsrc   = (float*)alloc((size_t)HEADS * HID * 4);
    float* vdst   = (float*)alloc((size_t)HEADS * HID * 4);

    // zero the padding rows (index N_NODES used by pad lanes)
    hipMemsetAsync(h  + (size_t)N_NODES * HID, 0, HID * 2, stream);
    hipMemsetAsync(h1 + (size_t)N_NODES * HID, 0, HID * 2, stream);

    // CSR build: atomic-free MSD bucket sort (hierarchical coalesced scan)
    histA   <<<NBLK_A, 256, 0, stream>>>(edge, ghist);
    scanB1  <<<NSB, 256, 0, stream>>>(ghist, bsum);
    scanB2  <<<1, 320, 0, stream>>>(bsum);
    scanB3  <<<NSB, 256, 0, stream>>>(ghist, bsum);
    scatterC<<<NBLK_A, 256, 0, stream>>>(edge, ghist, tmp);
    sortD   <<<NBKT, 256, 0, stream>>>(tmp, ghist, colidx, rowptr, dinv);

    // attention projection vectors
    attvec_k<<<1, 256, 0, stream>>>(W_gat, att_s, att_d, vsrc, vdst);

    // GCN
    gemm1   <<<(N_NODES + 31) / 32, 256, 0, stream>>>(x, W_gcn, dinv, h);
    gcn_agg <<<(N_NODES + 3) / 4, 256, 0, stream>>>(h, rowptr, colidx, dinv, b_gcn,
                                                    vsrc, vdst, h1, as_a, ad_a);

    // GAT
    gat_agg <<<(N_NODES + 3) / 4, 256, 0, stream>>>(h1, rowptr, colidx, as_a, ad_a, u);
    gemm2b  <<<625, 256, 0, stream>>>(u, W_gat, b_gat, h2);

    // FC
    gemm3   <<<256, 256, 0, stream>>>(h2, W_fc, b_fc, out);
}

// Round 14
// 253.150 us; speedup vs baseline: 1.1321x; 1.0407x over previous
//
#include <hip/hip_runtime.h>
#include <hip/hip_bf16.h>
#include <hip/hip_fp16.h>
#include <math.h>

#define N_NODES 50000
#define N_EDGES 1600000
#define D_IN    32
#define HID     64
#define HEADS   4
#define D_OUT   32
#define NEG_SLOPE 0.2f
#define CHUNK 128
#define NTILES 3125   // N_NODES / 16, exact

// MSD bucket-sort CSR build
#define NBKT 196      // d>>8 buckets (d < 50000)
#define NBLK_A 391    // ceil(1.6M / 4096)
#define TILE_A 4096
#define GH (NBKT * NBLK_A)   // 76636
#define NSB 300       // ceil(GH / 256)
#define CAP 10240     // max bucket size (avg 8163, sigma ~90 -> 23 sigma margin)

typedef _Float16 half8 __attribute__((ext_vector_type(8)));
typedef float    f32x4 __attribute__((ext_vector_type(4)));
typedef float    f32x2 __attribute__((ext_vector_type(2)));

// ---------------------------------------------------------------- CSR: pass A — per-block 196-bin histogram (LDS, per-wave replicas)
__global__ __launch_bounds__(256) void histA(const int* __restrict__ edge,
                                             int* __restrict__ ghist) {
    __shared__ int hist[4][NBKT];
    int t = threadIdx.x, wv = t >> 6;
    for (int i = t; i < 4 * NBKT; i += 256) ((int*)hist)[i] = 0;
    __syncthreads();
    int base = blockIdx.x * TILE_A;
#pragma unroll
    for (int k = 0; k < 16; k++) {
        int i = base + k * 256 + t;
        if (i < N_EDGES) atomicAdd(&hist[wv][edge[N_EDGES + i] >> 8], 1);
    }
    __syncthreads();
    for (int b = t; b < NBKT; b += 256)
        ghist[b * NBLK_A + blockIdx.x] = hist[0][b] + hist[1][b] + hist[2][b] + hist[3][b];
}

// ---------------------------------------------------------------- CSR: pass B — hierarchical coalesced scan of GH entries
__global__ __launch_bounds__(256) void scanB1(const int* __restrict__ g,
                                              int* __restrict__ bsum) {
    int t = threadIdx.x;
    int i = blockIdx.x * 256 + t;
    int v = (i < GH) ? g[i] : 0;              // coalesced
#pragma unroll
    for (int off = 32; off; off >>= 1) v += __shfl_xor(v, off);
    __shared__ int ws[4];
    if ((t & 63) == 0) ws[t >> 6] = v;
    __syncthreads();
    if (t == 0) bsum[blockIdx.x] = ws[0] + ws[1] + ws[2] + ws[3];
}

// block 0: scan of NSB block sums.  block 1: attention projection vectors (fused to save a launch).
__global__ __launch_bounds__(320) void scanB2_attvec(int* __restrict__ bsum,
                                                     const float* __restrict__ W,
                                                     const float* __restrict__ att_s,
                                                     const float* __restrict__ att_d,
                                                     float* __restrict__ vsrc,
                                                     float* __restrict__ vdst) {
    int t = threadIdx.x, lane = t & 63, wv = t >> 6;
    if (blockIdx.x == 0) {
        int v = (t < NSB) ? bsum[t] : 0;
        int inc = v;
#pragma unroll
        for (int d = 1; d < 64; d <<= 1) {
            int u = __shfl_up(inc, d);
            if (lane >= d) inc += u;
        }
        __shared__ int ws[5];
        if (lane == 63) ws[wv] = inc;
        __syncthreads();
        int add = 0;
#pragma unroll
        for (int j = 0; j < 5; j++) if (j < wv) add += ws[j];
        if (t < NSB) bsum[t] = add + inc - v;     // exclusive block offsets
    } else if (t < 256) {
        int h = t >> 6, k = t & 63;
        float s_ = 0.f, d_ = 0.f;
#pragma unroll 8
        for (int c = 0; c < 64; c++) {
            float w = W[k * 256 + h * 64 + c];
            s_ += w * att_s[h * 64 + c];
            d_ += w * att_d[h * 64 + c];
        }
        vsrc[h * 64 + k] = s_;
        vdst[h * 64 + k] = d_;
    }
}

__global__ __launch_bounds__(256) void scanB3(int* __restrict__ g,
                                              const int* __restrict__ bsum) {
    int t = threadIdx.x, lane = t & 63, wv = t >> 6;
    int i = blockIdx.x * 256 + t;
    int v = (i < GH) ? g[i] : 0;              // coalesced
    int inc = v;
#pragma unroll
    for (int d = 1; d < 64; d <<= 1) {
        int u = __shfl_up(inc, d);
        if (lane >= d) inc += u;
    }
    __shared__ int ws[4];
    if (lane == 63) ws[wv] = inc;
    __syncthreads();
    int add = 0;
#pragma unroll
    for (int j = 0; j < 4; j++) if (j < wv) add += ws[j];
    if (i < GH) g[i] = bsum[blockIdx.x] + add + inc - v;   // exclusive prefix
}

// ---------------------------------------------------------------- CSR: pass C — scatter packed (d<<16|s) via LDS cursors (disjoint global ranges)
__global__ __launch_bounds__(256) void scatterC(const int* __restrict__ edge,
                                                const int* __restrict__ ghist,
                                                unsigned* __restrict__ tmp) {
    __shared__ int cur[NBKT];
    int t = threadIdx.x;
    if (t < NBKT) cur[t] = ghist[t * NBLK_A + blockIdx.x];
    __syncthreads();
    int base = blockIdx.x * TILE_A;
#pragma unroll
    for (int k = 0; k < 16; k++) {
        int i = base + k * 256 + t;
        if (i < N_EDGES) {
            int s = edge[i], d = edge[N_EDGES + i];
            int pos = atomicAdd(&cur[d >> 8], 1);     // LDS atomic
            tmp[pos] = ((unsigned)d << 16) | (unsigned)s;
        }
    }
}

// ---------------------------------------------------------------- CSR: pass D — per-bucket 256-bin regroup; emits colidx(u16), rowptr, dinv
__global__ __launch_bounds__(256) void sortD(const unsigned* __restrict__ tmp,
                                             const int* __restrict__ ghist,
                                             unsigned short* __restrict__ colidx,
                                             int* __restrict__ rowptr,
                                             float* __restrict__ dinv) {
    __shared__ unsigned char  dl8[CAP];
    __shared__ unsigned short s16[CAP];
    __shared__ unsigned short o16[CAP];
    __shared__ int hist[4][256];
    __shared__ int excl[256];
    __shared__ int wsum[4];
    int t = threadIdx.x, lane = t & 63, wv = t >> 6;
    int b = blockIdx.x;
    int lo = ghist[b * NBLK_A];
    int hi = (b < NBKT - 1) ? ghist[(b + 1) * NBLK_A] : N_EDGES;
    int size = hi - lo;
    if (size > CAP) size = CAP;           // unreachable safety clamp
    for (int i = t; i < 4 * 256; i += 256) ((int*)hist)[i] = 0;
    __syncthreads();
    for (int i = t; i < size; i += 256) {
        unsigned key = tmp[lo + i];
        int dl = (key >> 16) & 255;
        dl8[i] = (unsigned char)dl;
        s16[i] = (unsigned short)(key & 0xFFFF);
        atomicAdd(&hist[wv][dl], 1);
    }
    __syncthreads();
    int h = hist[0][t] + hist[1][t] + hist[2][t] + hist[3][t];
    int inc = h;
#pragma unroll
    for (int d = 1; d < 64; d <<= 1) {
        int u = __shfl_up(inc, d);
        if (lane >= d) inc += u;
    }
    if (lane == 63) wsum[wv] = inc;
    __syncthreads();
    int add = 0;
#pragma unroll
    for (int j = 0; j < 4; j++) if (j < wv) add += wsum[j];
    int ex = inc - h + add;
    excl[t] = ex;
    int node = b * 256 + t;
    if (node < N_NODES) {
        rowptr[node] = lo + ex;
        dinv[node]   = rsqrtf((float)(h + 1));        // +1 self-loop
    }
    if (b == NBKT - 1 && t == 0) rowptr[N_NODES] = N_EDGES;
    __syncthreads();
    for (int i = t; i < size; i += 256) {
        int pos = atomicAdd(&excl[dl8[i]], 1);        // LDS cursor claim
        o16[pos] = s16[i];
    }
    __syncthreads();
    for (int i = t; i < size; i += 256) colidx[lo + i] = o16[i];
}

// ---------------------------------------------------------------- GEMM1: h = fp16( dinv .* (x @ W_gcn) ); block 0 zeros the pad rows
__global__ __launch_bounds__(256) void gemm1(const float* __restrict__ x,
                                             const float* __restrict__ W,
                                             const float* __restrict__ dinv,
                                             __half* __restrict__ h,
                                             __half* __restrict__ h1) {
    __shared__ float Wl[D_IN * HID];      // 8 KB
    int t = threadIdx.x;
    if (blockIdx.x == 0 && t < HID) {     // zero pad row N_NODES (read by pad lanes in agg kernels)
        h [(size_t)N_NODES * HID + t] = __float2half(0.f);
        h1[(size_t)N_NODES * HID + t] = __float2half(0.f);
    }
    for (int i = t; i < D_IN * HID; i += 256) Wl[i] = W[i];
    __syncthreads();
    int c = t & 63, rw = t >> 6;
    int r0 = blockIdx.x * 32;
#pragma unroll
    for (int rr = 0; rr < 8; rr++) {
        int r = r0 + rr * 4 + rw;
        if (r >= N_NODES) break;
        const float4* xr4 = (const float4*)(x + r * D_IN);
        float acc = 0.f;
#pragma unroll
        for (int k4 = 0; k4 < D_IN / 4; k4++) {
            float4 xv = xr4[k4];
            int k = k4 * 4;
            acc += xv.x * Wl[(k+0)*HID + c] + xv.y * Wl[(k+1)*HID + c]
                 + xv.z * Wl[(k+2)*HID + c] + xv.w * Wl[(k+3)*HID + c];
        }
        h[r * HID + c] = __float2half(acc * dinv[r]);
    }
}

// ---------------------------------------------------------------- GCN aggregate -> h1 fp16 (relu), fused attention dots
// Quarter layout (R11): 16 lanes/edge, lane holds 4 channels (8B dwordx2); 4 edges/iter.
__global__ __launch_bounds__(256) void gcn_agg(const __half* __restrict__ h,
                                               const int* __restrict__ rowptr,
                                               const unsigned short* __restrict__ colidx,
                                               const float* __restrict__ dinv,
                                               const float* __restrict__ b,
                                               const float* __restrict__ vsrc,
                                               const float* __restrict__ vdst,
                                               __half* __restrict__ h1,
                                               float* __restrict__ as_o,
                                               float* __restrict__ ad_o) {
    __shared__ int sbuf[4][CHUNK + 4];
    int lane = threadIdx.x & 63, wv = threadIdx.x >> 6;
    int quarter = lane >> 4, ql = lane & 15;
    int n = blockIdx.x * 4 + wv;
    if (n >= N_NODES) return;
    int rp = rowptr[n], re = rowptr[n + 1];
    f32x2 a01 = {0.f, 0.f}, a23 = {0.f, 0.f};
    const __half* hp = h + ql * 4;
    for (int cb = rp; cb < re; cb += CHUNK) {
        int ce = min(cb + CHUNK, re);
        for (int e = cb + lane; e < ce; e += 64) sbuf[wv][e - cb] = colidx[e];
        int m = ce - cb;
        int pad = (4 - (m & 3)) & 3;
        if (lane < pad) sbuf[wv][m + lane] = N_NODES;   // zero row
        int m4 = (m + pad) >> 2;
#pragma unroll 2
        for (int i = 0; i < m4; i++) {
            int s = sbuf[wv][i * 4 + quarter];
            float2 raw = *(const float2*)(hp + s * HID);    // 4 fp16
            __half2 g0 = __builtin_bit_cast(__half2, raw.x);
            __half2 g1 = __builtin_bit_cast(__half2, raw.y);
            float2 f0 = __half22float2(g0), f1 = __half22float2(g1);
            a01.x += f0.x; a01.y += f0.y;
            a23.x += f1.x; a23.y += f1.y;
        }
    }
    // combine quarters (xor 16, 32)
#pragma unroll
    for (int off = 16; off <= 32; off <<= 1) {
        a01.x += __shfl_xor(a01.x, off); a01.y += __shfl_xor(a01.y, off);
        a23.x += __shfl_xor(a23.x, off); a23.y += __shfl_xor(a23.y, off);
    }
    // self-loop contribution (h pre-scaled by dinv[n]) — quarter-0 lanes only
    if (quarter == 0) {
        float2 raw = *(const float2*)(hp + n * HID);
        __half2 g0 = __builtin_bit_cast(__half2, raw.x);
        __half2 g1 = __builtin_bit_cast(__half2, raw.y);
        float2 f0 = __half22float2(g0), f1 = __half22float2(g1);
        a01.x += f0.x; a01.y += f0.y;
        a23.x += f1.x; a23.y += f1.y;
    }
    float dn = dinv[n];
    const float4 bb = *(const float4*)&b[ql * 4];
    float v0 = fmaxf(a01.x * dn + bb.x, 0.f);
    float v1 = fmaxf(a01.y * dn + bb.y, 0.f);
    float v2 = fmaxf(a23.x * dn + bb.z, 0.f);
    float v3 = fmaxf(a23.y * dn + bb.w, 0.f);
    if (quarter == 0) {
        __half2* op = (__half2*)&h1[n * HID + ql * 4];
        op[0] = __floats2half2_rn(v0, v1);
        op[1] = __floats2half2_rn(v2, v3);
    }
    // attention dots (quarter-0 values feed lane 0's write)
#pragma unroll
    for (int hh = 0; hh < 4; hh++) {
        float4 vsp = *(const float4*)&vsrc[hh * 64 + ql * 4];
        float4 vdp = *(const float4*)&vdst[hh * 64 + ql * 4];
        float vs = v0 * vsp.x + v1 * vsp.y + v2 * vsp.z + v3 * vsp.w;
        float vd = v0 * vdp.x + v1 * vdp.y + v2 * vdp.z + v3 * vdp.w;
#pragma unroll
        for (int off = 8; off > 0; off >>= 1) {
            vs += __shfl_xor(vs, off);
            vd += __shfl_xor(vd, off);
        }
        if (lane == 0) {
            as_o[n * 4 + hh] = vs;
            ad_o[n * 4 + hh] = vd;
        }
    }
}

// ---------------------------------------------------------------- GAT aggregate (no max pass; self-loop analytic) -> u fp16
// Quarter layout (R11): 16 lanes/edge, 8B dwordx2 loads, 4 edges/iter.
__global__ __launch_bounds__(256) void gat_agg(const __half* __restrict__ h1,
                                               const int* __restrict__ rowptr,
                                               const unsigned short* __restrict__ colidx,
                                               const float* __restrict__ a_s,
                                               const float* __restrict__ a_d,
                                               __half* __restrict__ u) {
    __shared__ float wbuf[4][(CHUNK + 4) * 4];
    __shared__ int   sbuf[4][CHUNK + 4];
    int lane = threadIdx.x & 63, wv = threadIdx.x >> 6;
    int quarter = lane >> 4, ql = lane & 15;
    int n = blockIdx.x * 4 + wv;
    if (n >= N_NODES) return;
    int rp = rowptr[n], re = rowptr[n + 1];
    float4 ad4 = *(const float4*)&a_d[n * 4];
    float4 asn = *(const float4*)&a_s[n * 4];

    float dnx = 0.f, dny = 0.f, dnz = 0.f, dnw = 0.f;
    f32x2 acc[4][2];
#pragma unroll
    for (int hh = 0; hh < 4; hh++) { acc[hh][0] = (f32x2){0.f,0.f}; acc[hh][1] = (f32x2){0.f,0.f}; }
    const __half* hp = h1 + ql * 4;
    for (int cb = rp; cb < re; cb += CHUNK) {
        int ce = min(cb + CHUNK, re);
        // phase B: distributed weights -> LDS (no clamp: logits are O(+-6), fp32 exp safe)
        for (int e = cb + lane; e < ce; e += 64) {
            int s = colidx[e];
            float4 a = *(const float4*)&a_s[s * 4];
            float vx = a.x + ad4.x; vx = fmaxf(vx, NEG_SLOPE * vx);
            float vy = a.y + ad4.y; vy = fmaxf(vy, NEG_SLOPE * vy);
            float vz = a.z + ad4.z; vz = fmaxf(vz, NEG_SLOPE * vz);
            float vw = a.w + ad4.w; vw = fmaxf(vw, NEG_SLOPE * vw);
            float wx = __expf(vx), wy = __expf(vy);
            float wz = __expf(vz), ww = __expf(vw);
            dnx += wx; dny += wy; dnz += wz; dnw += ww;
            int idx = e - cb;
            *(float4*)&wbuf[wv][idx * 4] = make_float4(wx, wy, wz, ww);
            sbuf[wv][idx] = s;
        }
        int m = ce - cb;
        int pad = (4 - (m & 3)) & 3;
        if (lane < pad) {
            sbuf[wv][m + lane] = N_NODES;
            *(float4*)&wbuf[wv][(m + lane) * 4] = make_float4(0.f, 0.f, 0.f, 0.f);
        }
        int m4 = (m + pad) >> 2;
#pragma unroll 2
        for (int i = 0; i < m4; i++) {
            int idx = i * 4 + quarter;
            int s = sbuf[wv][idx];
            float4 w4 = *(const float4*)&wbuf[wv][idx * 4];
            float2 raw = *(const float2*)(hp + s * HID);
            __half2 g0 = __builtin_bit_cast(__half2, raw.x);
            __half2 g1 = __builtin_bit_cast(__half2, raw.y);
            float2 t0 = __half22float2(g0), t1 = __half22float2(g1);
            f32x2 f0 = {t0.x, t0.y}, f1 = {t1.x, t1.y};
            f32x2 wx2 = {w4.x, w4.x}, wy2 = {w4.y, w4.y};
            f32x2 wz2 = {w4.z, w4.z}, ww2 = {w4.w, w4.w};
            acc[0][0] += wx2 * f0; acc[0][1] += wx2 * f1;
            acc[1][0] += wy2 * f0; acc[1][1] += wy2 * f1;
            acc[2][0] += wz2 * f0; acc[2][1] += wz2 * f1;
            acc[3][0] += ww2 * f0; acc[3][1] += ww2 * f1;
        }
    }
    // combine quarters
#pragma unroll
    for (int hh = 0; hh < 4; hh++)
#pragma unroll
        for (int c = 0; c < 2; c++) {
            acc[hh][c].x += __shfl_xor(acc[hh][c].x, 16);
            acc[hh][c].y += __shfl_xor(acc[hh][c].y, 16);
            acc[hh][c].x += __shfl_xor(acc[hh][c].x, 32);
            acc[hh][c].y += __shfl_xor(acc[hh][c].y, 32);
        }
    // reduce denominators
#pragma unroll
    for (int off = 32; off > 0; off >>= 1) {
        dnx += __shfl_xor(dnx, off);
        dny += __shfl_xor(dny, off);
        dnz += __shfl_xor(dnz, off);
        dnw += __shfl_xor(dnw, off);
    }
    // self-loop: w_self per head (wave-uniform)
    float sx = asn.x + ad4.x; sx = fmaxf(sx, NEG_SLOPE * sx);
    float sy = asn.y + ad4.y; sy = fmaxf(sy, NEG_SLOPE * sy);
    float sz = asn.z + ad4.z; sz = fmaxf(sz, NEG_SLOPE * sz);
    float sw = asn.w + ad4.w; sw = fmaxf(sw, NEG_SLOPE * sw);
    float wsx = __expf(sx), wsy = __expf(sy);
    float wsz = __expf(sz), wsw = __expf(sw);
    dnx += wsx; dny += wsy; dnz += wsz; dnw += wsw;
    if (quarter == 0) {
        float2 raw = *(const float2*)(hp + n * HID);
        __half2 g0 = __builtin_bit_cast(__half2, raw.x);
        __half2 g1 = __builtin_bit_cast(__half2, raw.y);
        float2 t0 = __half22float2(g0), t1 = __half22float2(g1);
        acc[0][0].x += wsx * t0.x; acc[0][0].y += wsx * t0.y; acc[0][1].x += wsx * t1.x; acc[0][1].y += wsx * t1.y;
        acc[1][0].x += wsy * t0.x; acc[1][0].y += wsy * t0.y; acc[1][1].x += wsy * t1.x; acc[1][1].y += wsy * t1.y;
        acc[2][0].x += wsz * t0.x; acc[2][0].y += wsz * t0.y; acc[2][1].x += wsz * t1.x; acc[2][1].y += wsz * t1.y;
        acc[3][0].x += wsw * t0.x; acc[3][0].y += wsw * t0.y; acc[3][1].x += wsw * t1.x; acc[3][1].y += wsw * t1.y;
        float r4[4] = {1.f / dnx, 1.f / dny, 1.f / dnz, 1.f / dnw};
        __half* up = u + n * 256 + ql * 4;
#pragma unroll
        for (int hh = 0; hh < 4; hh++) {
            __half2* op = (__half2*)&up[hh * 64];
            op[0] = __floats2half2_rn(acc[hh][0].x * r4[hh], acc[hh][0].y * r4[hh]);
            op[1] = __floats2half2_rn(acc[hh][1].x * r4[hh], acc[hh][1].y * r4[hh]);
        }
    }
}

// ---------------------------------------------------------------- gemm2b (MFMA): h2 = fp16 relu(u @ blockdiag(W_gat) + b)
__global__ __launch_bounds__(256) void gemm2b(const __half* __restrict__ u,
                                              const float* __restrict__ W,
                                              const float* __restrict__ b,
                                              __half* __restrict__ h2) {
    int lane = threadIdx.x & 63, hd = threadIdx.x >> 6;
    int quad = lane >> 4, l16 = lane & 15;
    half8 Bf[4][2];
#pragma unroll
    for (int nt = 0; nt < 4; nt++)
#pragma unroll
        for (int kc = 0; kc < 2; kc++) {
            const float* wp = W + (kc * 32 + quad * 8) * 256 + hd * 64 + nt * 16 + l16;
#pragma unroll
            for (int j = 0; j < 8; j++)
                Bf[nt][kc][j] = (_Float16)wp[j * 256];
        }
    float bb[4];
#pragma unroll
    for (int nt = 0; nt < 4; nt++) bb[nt] = b[hd * 64 + nt * 16 + l16];

    int rt0 = blockIdx.x * 5;
#pragma unroll
    for (int i = 0; i < 5; i++) {
        int rt = rt0 + i;
        const __half* up = u + ((size_t)(rt * 16 + l16)) * 256 + hd * 64 + quad * 8;
        half8 A0 = *(const half8*)(const void*)up;
        half8 A1 = *(const half8*)(const void*)(up + 32);
        f32x4 acc[4];
#pragma unroll
        for (int nt = 0; nt < 4; nt++) {
            acc[nt] = (f32x4){0.f, 0.f, 0.f, 0.f};
            acc[nt] = __builtin_amdgcn_mfma_f32_16x16x32_f16(A0, Bf[nt][0], acc[nt], 0, 0, 0);
            acc[nt] = __builtin_amdgcn_mfma_f32_16x16x32_f16(A1, Bf[nt][1], acc[nt], 0, 0, 0);
        }
#pragma unroll
        for (int nt = 0; nt < 4; nt++) {
            int col = hd * 64 + nt * 16 + l16;
#pragma unroll
            for (int reg = 0; reg < 4; reg++) {
                int row = rt * 16 + quad * 4 + reg;
                h2[(size_t)row * 256 + col] = __float2half(fmaxf(acc[nt][reg] + bb[nt], 0.f));
            }
        }
    }
}

// ---------------------------------------------------------------- gemm3 (MFMA): out = h2 @ W_fc + b_fc
__global__ __launch_bounds__(256) void gemm3(const __half* __restrict__ h2,
                                             const float* __restrict__ W,
                                             const float* __restrict__ b,
                                             float* __restrict__ out) {
    int lane = threadIdx.x & 63, wv = threadIdx.x >> 6;
    int quad = lane >> 4, l16 = lane & 15;
    half8 Bf[2][8];
#pragma unroll
    for (int nt = 0; nt < 2; nt++)
#pragma unroll
        for (int kc = 0; kc < 8; kc++) {
            const float* wp = W + (kc * 32 + quad * 8) * 32 + nt * 16 + l16;
#pragma unroll
            for (int j = 0; j < 8; j++)
                Bf[nt][kc][j] = (_Float16)wp[j * 32];
        }
    float bb0 = b[l16], bb1 = b[16 + l16];

    for (int tile = blockIdx.x * 4 + wv; tile < NTILES; tile += gridDim.x * 4) {
        const __half* hp = h2 + (size_t)(tile * 16 + l16) * 256 + quad * 8;
        f32x4 acc0 = {0.f, 0.f, 0.f, 0.f};
        f32x4 acc1 = {0.f, 0.f, 0.f, 0.f};
#pragma unroll
        for (int kc = 0; kc < 8; kc++) {
            half8 A = *(const half8*)(const void*)(hp + kc * 32);
            acc0 = __builtin_amdgcn_mfma_f32_16x16x32_f16(A, Bf[0][kc], acc0, 0, 0, 0);
            acc1 = __builtin_amdgcn_mfma_f32_16x16x32_f16(A, Bf[1][kc], acc1, 0, 0, 0);
        }
#pragma unroll
        for (int reg = 0; reg < 4; reg++) {
            int row = tile * 16 + quad * 4 + reg;
            out[row * 32 + l16]      = acc0[reg] + bb0;
            out[row * 32 + 16 + l16] = acc1[reg] + bb1;
        }
    }
}

// ---------------------------------------------------------------- launch
extern "C" void kernel_launch(void* const* d_in, const int* in_sizes, int n_in,
                              void* d_out, int out_size, void* d_ws, size_t ws_size,
                              hipStream_t stream) {
    const float* x      = (const float*)d_in[0];
    const int*   edge   = (const int*)  d_in[1];
    const float* W_gcn  = (const float*)d_in[2];
    const float* b_gcn  = (const float*)d_in[3];
    const float* W_gat  = (const float*)d_in[4];
    const float* att_s  = (const float*)d_in[5];
    const float* att_d  = (const float*)d_in[6];
    const float* b_gat  = (const float*)d_in[7];
    const float* W_fc   = (const float*)d_in[8];
    const float* b_fc   = (const float*)d_in[9];
    float* out = (float*)d_out;

    char* p = (char*)d_ws;
    auto alloc = [&](size_t bytes) {
        char* q = p;
        p += (bytes + 255) & ~(size_t)255;
        return q;
    };
    __half* h     = (__half*)alloc((size_t)(N_NODES + 1) * HID * 2);   // +1 zero row
    __half* h1    = (__half*)alloc((size_t)(N_NODES + 1) * HID * 2);   // +1 zero row
    __half* u     = (__half*)alloc((size_t)N_NODES * 256 * 2);
    __half* h2    = (__half*)alloc((size_t)N_NODES * 256 * 2);
    float* as_a   = (float*)alloc((size_t)N_NODES * 4 * 4);
    float* ad_a   = (float*)alloc((size_t)N_NODES * 4 * 4);
    float* dinv   = (float*)alloc((size_t)N_NODES * 4);
    int*   rowptr = (int*)  alloc((size_t)(N_NODES + 1) * 4);
    unsigned short* colidx = (unsigned short*)alloc((size_t)N_EDGES * 2);
    int*   ghist  = (int*)  alloc((size_t)GH * 4);
    int*   bsum   = (int*)  alloc((size_t)NSB * 4);
    unsigned* tmp = (unsigned*)alloc((size_t)N_EDGES * 4);
    float* vsrc   = (float*)alloc((size_t)HEADS * HID * 4);
    float* vdst   = (float*)alloc((size_t)HEADS * HID * 4);

    // CSR build: atomic-free MSD bucket sort (hierarchical coalesced scan; attvec fused into scanB2)
    histA        <<<NBLK_A, 256, 0, stream>>>(edge, ghist);
    scanB1       <<<NSB, 256, 0, stream>>>(ghist, bsum);
    scanB2_attvec<<<2, 320, 0, stream>>>(bsum, W_gat, att_s, att_d, vsrc, vdst);
    scanB3       <<<NSB, 256, 0, stream>>>(ghist, bsum);
    scatterC     <<<NBLK_A, 256, 0, stream>>>(edge, ghist, tmp);
    sortD        <<<NBKT, 256, 0, stream>>>(tmp, ghist, colidx, rowptr, dinv);

    // GCN (gemm1 also zeroes the pad rows of h/h1)
    gemm1   <<<(N_NODES + 31) / 32, 256, 0, stream>>>(x, W_gcn, dinv, h, h1);
    gcn_agg <<<(N_NODES + 3) / 4, 256, 0, stream>>>(h, rowptr, colidx, dinv, b_gcn,
                                                    vsrc, vdst, h1, as_a, ad_a);

    // GAT
    gat_agg <<<(N_NODES + 3) / 4, 256, 0, stream>>>(h1, rowptr, colidx, as_a, ad_a, u);
    gemm2b  <<<625, 256, 0, stream>>>(u, W_gat, b_gat, h2);

    // FC
    gemm3   <<<256, 256, 0, stream>>>(h2, W_fc, b_fc, out);
}